// Round 16
// baseline (174.408 us; speedup 1.0000x reference)
//
#include <hip/hip_runtime.h>
#include <stdint.h>

typedef __attribute__((ext_vector_type(8))) short bf16x8;   // 8 bf16 = 4 VGPRs
typedef __attribute__((ext_vector_type(4))) float f32x4;
typedef __attribute__((ext_vector_type(8))) int i32x8;      // 32 B fp8 operand (8 VGPRs)

#define DEVI __device__ __forceinline__

DEVI unsigned short f2bf(float f) {
    union { float f; uint32_t u; } v; v.f = f;
    uint32_t r = v.u + 0x7FFFu + ((v.u >> 16) & 1u);   // RNE
    return (unsigned short)(r >> 16);
}
DEVI float bf2f(unsigned short h) {
    union { uint32_t u; float f; } v; v.u = ((uint32_t)h) << 16;
    return v.f;
}
DEVI bf16x8 pack8(float4 a, float4 b) {
    bf16x8 o;
    o[0]=(short)f2bf(a.x); o[1]=(short)f2bf(a.y); o[2]=(short)f2bf(a.z); o[3]=(short)f2bf(a.w);
    o[4]=(short)f2bf(b.x); o[5]=(short)f2bf(b.y); o[6]=(short)f2bf(b.z); o[7]=(short)f2bf(b.w);
    return o;
}

// software fp32 -> OCP e4m3fn, RNE (no API dependency)
DEVI unsigned char f2e4m3(float x) {
    union { float f; uint32_t u; } v; v.f = x;
    uint32_t sign = (v.u >> 24) & 0x80u;
    v.u &= 0x7FFFFFFFu;
    if (v.f >= 464.f) return (unsigned char)(sign | 0x7Eu);          // clamp to 448
    if (v.f < 0.0009765625f) return (unsigned char)sign;             // < 2^-10 -> 0
    uint32_t e = v.u >> 23;
    float q = __builtin_rintf(v.f * 512.f);                          // subnormal: mult of 2^-9
    uint32_t ms = (uint32_t)q;
    uint32_t subres = sign | (ms >= 8u ? 0x08u : ms);
    uint32_t r = v.u + 0x7FFFFu + ((v.u >> 20) & 1u);                // RNE to 3 mantissa bits
    uint32_t er = r >> 23;
    uint32_t normres = (er > 135u) ? (sign | 0x7Eu)
                                   : (sign | ((er - 120u) << 3) | ((r >> 20) & 7u));
    return (unsigned char)((e < 121u) ? subres : normres);
}

// exact branchless e4m3 -> fp32 (subnormals exact)
DEVI float e4m3f(unsigned char u) {
    union { uint32_t u; float f; } v;
    v.u = (((uint32_t)u & 0x80u) << 24) | (((uint32_t)u & 0x7Fu) << 20);
    return v.f * 0x1p120f;
}

#define GLOAD_LDS16(gsrc, ldst) \
    __builtin_amdgcn_global_load_lds((__attribute__((address_space(1))) void*)(gsrc), \
                                     (__attribute__((address_space(3))) void*)(ldst), 16, 0, 0)

#define BARR asm volatile("s_barrier" ::: "memory")
#define WAITV(n) asm volatile("s_waitcnt vmcnt(" #n ")" ::: "memory")

// ---------------- prep: conversions only (es fp8, U_w fp8, W_w/fc_w bf16, hidden) -----------
// B0/B1 GRU-weight assembly moved into the u-GEMM blocks' tails (soaks its idle HBM BW).
__global__ void k_prep(const float* __restrict__ es, const float* __restrict__ U_w,
                       const float* __restrict__ W_w, const float* __restrict__ fc_w,
                       const float* __restrict__ hidden,
                       unsigned char* __restrict__ ES_F8, unsigned char* __restrict__ UW_F8,
                       unsigned short* __restrict__ WW_BF, unsigned short* __restrict__ FCW_BF,
                       unsigned short* __restrict__ A0, unsigned short* __restrict__ A1,
                       unsigned short* __restrict__ H1B) {
    int i = blockIdx.x * blockDim.x + threadIdx.x;
    const int S0 = 4194304, S1 = S0 + 262144, S2 = S1 + 131072, S3 = S2 + 16384;
    const int S4 = S3 + 32768;                          // total 4,636,672 chunks
    if (i < S0) {
        const float4* s = (const float4*)(es + (size_t)i * 8);
        float4 a = s[0], b = s[1];
        float vv[8] = {a.x, a.y, a.z, a.w, b.x, b.y, b.z, b.w};
        unsigned long long p8 = 0;
        #pragma unroll
        for (int k = 0; k < 8; ++k) p8 |= (unsigned long long)f2e4m3(vv[k]) << (8 * k);
        *(unsigned long long*)(ES_F8 + (size_t)i * 8) = p8;
    } else if (i < S1) {
        int j = i - S0;
        const float4* s = (const float4*)(U_w + (size_t)j * 8);
        float4 a = s[0], b = s[1];
        float vv[8] = {a.x, a.y, a.z, a.w, b.x, b.y, b.z, b.w};
        unsigned long long p8 = 0;
        #pragma unroll
        for (int k = 0; k < 8; ++k) p8 |= (unsigned long long)f2e4m3(vv[k] * 16.f) << (8 * k);
        *(unsigned long long*)(UW_F8 + (size_t)j * 8) = p8;     // U_w scaled x16 (epilogue /16)
    } else if (i < S2) {
        int j = i - S1;
        const float4* s = (const float4*)(W_w + (size_t)j * 8);
        *(bf16x8*)(WW_BF + (size_t)j * 8) = pack8(s[0], s[1]);
    } else if (i < S3) {
        int j = i - S2;
        const float4* s = (const float4*)(fc_w + (size_t)j * 8);
        *(bf16x8*)(FCW_BF + (size_t)j * 8) = pack8(s[0], s[1]);
    } else if (i < S4) {
        int j = i - S3;
        int n = j >> 7, e0 = (j & 127) * 8;
        const float4* p0 = (const float4*)(hidden + (size_t)n * 1024 + e0);
        const float4* p1 = (const float4*)(hidden + 262144 + (size_t)n * 1024 + e0);
        bf16x8 o0 = pack8(p0[0], p0[1]);
        bf16x8 o1 = pack8(p1[0], p1[1]);
        *(bf16x8*)(A0 + (size_t)n * 3328 + 2304 + e0) = o0;
        *(bf16x8*)(A1 + (size_t)n * 2048 + 1024 + e0) = o1;
        *(bf16x8*)(H1B + (size_t)n * 1024 + e0) = o1;
    }
}

// ---------------- split-K GEMM, R8 shell: Cpart[z] = A(MxK[slice z]) * B(NxK)^T (bf16) -------
__global__ __launch_bounds__(256) void gemm_bt_sk2(
        const unsigned short* __restrict__ A, const unsigned short* __restrict__ B,
        float* __restrict__ Cpart, int K, int ksl) {
    __shared__ __align__(16) char lds[65536];           // 2 slots x 32 KiB
    const int NTT = ksl >> 6;

    const int t = threadIdx.x;
    const int w = t >> 6, lane = t & 63;
    const int wm = w >> 1, wn = w & 1;
    const int lg = lane >> 4, r16 = lane & 15;
    const int z = blockIdx.z;
    const int nbx = gridDim.x;
    const int N = nbx * 128, M = gridDim.y * 128;

    int d = blockIdx.y * nbx + blockIdx.x;
    int f = d;
    int nwg = nbx * gridDim.y;
    if ((nwg & 7) == 0) { int cpx = nwg >> 3; f = (d & 7) * cpx + (d >> 3); }
    const int bx = f % nbx, by = f / nbx;
    const int row0 = by * 128, col0 = bx * 128;

    const unsigned short* gsrc[8];
    unsigned lodst[8];
    #pragma unroll
    for (int q = 0; q < 8; ++q) {
        int isB = q >> 2, rq = q & 3;
        int row = rq * 32 + w * 8 + (lane >> 3);
        int slot = (lane & 7) ^ (lane >> 3);
        gsrc[q] = (isB ? B + (size_t)(col0 + row) * K
                       : A + (size_t)(row0 + row) * K) + (size_t)z * ksl + slot * 8;
        lodst[q] = (unsigned)(isB * 16384 + (rq * 32 + w * 8) * 128);
    }

#define STAGE(T) do { \
    char* lp_ = lds + ((T) & 1) * 32768; \
    _Pragma("unroll") \
    for (int q_ = 0; q_ < 8; ++q_) \
        GLOAD_LDS16(gsrc[q_] + (size_t)(T) * 64, lp_ + lodst[q_]); \
} while (0)

    const unsigned swz = (unsigned)((r16 & 7) << 4);
    unsigned aoff[4], boff[4];
    #pragma unroll
    for (int m = 0; m < 4; ++m)
        aoff[m] = ((unsigned)((wm * 64 + m * 16 + r16) * 128 + lg * 16)) ^ swz;
    #pragma unroll
    for (int n = 0; n < 4; ++n)
        boff[n] = 16384u + (((unsigned)((wn * 64 + n * 16 + r16) * 128 + lg * 16)) ^ swz);

    f32x4 acc[4][4];
    #pragma unroll
    for (int m = 0; m < 4; ++m)
        #pragma unroll
        for (int n = 0; n < 4; ++n)
            #pragma unroll
            for (int q = 0; q < 4; ++q) acc[m][n][q] = 0.0f;

    STAGE(0);
    #pragma unroll 1
    for (int tt = 0; tt < NTT; ++tt) {
        if (tt + 1 < NTT) { STAGE(tt + 1); WAITV(8); }
        else              { WAITV(0); }
        BARR;
        const char* lp = lds + (tt & 1) * 32768;
        #pragma unroll
        for (int kk = 0; kk < 2; ++kk) {
            bf16x8 afr[4], bfr[4];
            #pragma unroll
            for (int n = 0; n < 4; ++n) bfr[n] = *(const bf16x8*)(lp + (boff[n] ^ (kk << 6)));
            #pragma unroll
            for (int m = 0; m < 4; ++m) afr[m] = *(const bf16x8*)(lp + (aoff[m] ^ (kk << 6)));
            #pragma unroll
            for (int m = 0; m < 4; ++m)
                #pragma unroll
                for (int n = 0; n < 4; ++n)
                    acc[m][n] = __builtin_amdgcn_mfma_f32_16x16x32_bf16(
                        afr[m], bfr[n], acc[m][n], 0, 0, 0);
        }
        BARR;
    }
#undef STAGE

    float* Cz = Cpart + (size_t)z * (size_t)M * N;
    #pragma unroll
    for (int m = 0; m < 4; ++m)
        #pragma unroll
        for (int n = 0; n < 4; ++n)
            #pragma unroll
            for (int q = 0; q < 4; ++q) {
                int row = row0 + wm * 64 + m * 16 + lg * 4 + q;
                int col = col0 + wn * 64 + n * 16 + r16;
                Cz[(size_t)row * N + col] = acc[m][n][q];
            }
}

// ---------------- u-GEMM fp8 (MX K=128, unit scales, R12 read slots) + B0/B1 ride-along -----
// GEMM identical to R15 (0-conflict). Tail: each of the 1024 blocks assembles 2688 chunks of
// the fused GRU weights B0/B1 (bf16) after its epilogue — soaks the GEMM's ~90% idle HBM BW
// via co-resident-block overlap (m114). B0/B1 first consumed two launches later (GRU0).
__global__ __launch_bounds__(256) void gemm_energy128_f8(
        const unsigned char* __restrict__ A, const unsigned char* __restrict__ B,
        const float* __restrict__ attn_w, const float* __restrict__ U_b,
        const float* __restrict__ W_b, const float* __restrict__ WP,
        const float* __restrict__ Wih0, const float* __restrict__ Whh0,
        const float* __restrict__ Wih1, const float* __restrict__ Whh1,
        unsigned short* __restrict__ B0, unsigned short* __restrict__ B1,
        float* __restrict__ e_part) {
    const int NTT = 16;                                 // 2048 / 128, full K
    __shared__ __align__(16) char lds[65536];

    const int t = threadIdx.x;
    const int w = t >> 6, lane = t & 63;
    const int wm = w >> 1, wn = w & 1;
    const int lg = lane >> 4, r16 = lane & 15;

    int d = blockIdx.y * gridDim.x + blockIdx.x;        // 1024 blocks
    int f = (d & 7) * 128 + (d >> 3);                   // bijective XCD swizzle
    const int bx = f & 7, by = f >> 3;
    const int row0 = by * 128, col0 = bx * 128;

    const unsigned char* gsrc[8];
    unsigned lodst[8];
    #pragma unroll
    for (int q = 0; q < 8; ++q) {
        int isB = q >> 2, rq = q & 3;
        int row = rq * 32 + w * 8 + (lane >> 3);
        int slot = (lane & 7) ^ (lane >> 3);
        gsrc[q] = (isB ? B + (size_t)(col0 + row) * 2048
                       : A + (size_t)(row0 + row) * 2048) + slot * 16;
        lodst[q] = (unsigned)(isB * 16384 + (rq * 32 + w * 8) * 128);
    }

#define STAGE(T) do { \
    char* lp_ = lds + ((T) & 1) * 32768; \
    _Pragma("unroll") \
    for (int q_ = 0; q_ < 8; ++q_) \
        GLOAD_LDS16(gsrc[q_] + (size_t)(T) * 128, lp_ + lodst[q_]); \
} while (0)

    // R12-proven 0-conflict read slots: sel in {0,1} -> logical slot sel*4+lg, swz ^ (r16&7)
    unsigned s16[2];
    #pragma unroll
    for (int sel = 0; sel < 2; ++sel)
        s16[sel] = (unsigned)(((sel * 4 + lg) ^ (r16 & 7)) << 4);
    unsigned arow[4], brow[4];
    #pragma unroll
    for (int m = 0; m < 4; ++m) arow[m] = (unsigned)((wm * 64 + m * 16 + r16) * 128);
    #pragma unroll
    for (int n = 0; n < 4; ++n) brow[n] = 16384u + (unsigned)((wn * 64 + n * 16 + r16) * 128);

    f32x4 acc[4][4];
    #pragma unroll
    for (int m = 0; m < 4; ++m)
        #pragma unroll
        for (int n = 0; n < 4; ++n)
            #pragma unroll
            for (int q = 0; q < 4; ++q) acc[m][n][q] = 0.0f;

    STAGE(0);
    #pragma unroll 1
    for (int tt = 0; tt < NTT; ++tt) {
        if (tt + 1 < NTT) { STAGE(tt + 1); WAITV(8); }
        else              { WAITV(0); }
        BARR;
        const char* lp = lds + (tt & 1) * 32768;
        i32x8 a8[4], b8[4];
        #pragma unroll
        for (int n = 0; n < 4; ++n) {
            int4 lo = *(const int4*)(lp + brow[n] + s16[0]);
            int4 hi = *(const int4*)(lp + brow[n] + s16[1]);
            b8[n] = (i32x8){lo.x, lo.y, lo.z, lo.w, hi.x, hi.y, hi.z, hi.w};
        }
        #pragma unroll
        for (int m = 0; m < 4; ++m) {
            int4 lo = *(const int4*)(lp + arow[m] + s16[0]);
            int4 hi = *(const int4*)(lp + arow[m] + s16[1]);
            a8[m] = (i32x8){lo.x, lo.y, lo.z, lo.w, hi.x, hi.y, hi.z, hi.w};
        }
        #pragma unroll
        for (int m = 0; m < 4; ++m)
            #pragma unroll
            for (int n = 0; n < 4; ++n)
                acc[m][n] = __builtin_amdgcn_mfma_scale_f32_16x16x128_f8f6f4(
                    a8[m], b8[n], acc[m][n], 0, 0,
                    0, 0x7F7F7F7F, 0, 0x7F7F7F7F);     // unit E8M0 scales -> plain fp8
        BARR;
    }
#undef STAGE

    // fused energy epilogue; u = acc/16; w = 4 split-K partials + W_b inline (WP L2-resident)
    float aw[4], ub[4];
    #pragma unroll
    for (int n = 0; n < 4; ++n) {
        int col = col0 + wn * 64 + n * 16 + r16;
        aw[n] = attn_w[col];
        ub[n] = U_b[col] + W_b[col];
    }
    #pragma unroll
    for (int m = 0; m < 4; ++m)
        #pragma unroll
        for (int q = 0; q < 4; ++q) {
            int row = row0 + wm * 64 + m * 16 + lg * 4 + q;
            const float* wrow = WP + (size_t)(row & 255) * 1024;
            float e = 0.f;
            #pragma unroll
            for (int n = 0; n < 4; ++n) {
                int col = col0 + wn * 64 + n * 16 + r16;
                float wv = wrow[col] + wrow[262144 + col] + wrow[524288 + col] + wrow[786432 + col];
                float cc = acc[m][n][q] * 0.0625f + ub[n] + wv;
                float ex = __expf(2.f * cc);               // tanh via exp
                e += aw[n] * (1.f - 2.f / (ex + 1.f));
            }
            e += __shfl_xor(e, 1); e += __shfl_xor(e, 2);
            e += __shfl_xor(e, 4); e += __shfl_xor(e, 8);
            if (r16 == 0) e_part[(size_t)row * 16 + bx * 2 + wn] = e;
        }

    // ---- ride-along tail: B0/B1 assembly, 2688 chunks per block ----
    {
        int cbase = d * 2688 + t;                       // block-contiguous chunk range
        #pragma unroll 1
        for (int c = 0; c < 11; ++c) {
            int off_in_blk = t + c * 256;
            if (off_in_blk >= 2688) break;
            int j = cbase + c * 256;
            if (j < 1703936) {                          // B0 (4096 x 3328)
                unsigned r = (unsigned)j / 416u;
                int kc = (int)((unsigned)j - r * 416u) * 8;
                const float* src = nullptr;
                if (r < 2048)      src = (kc < 2304) ? (Wih0 + (size_t)r * 2304 + kc)
                                                     : (Whh0 + (size_t)r * 1024 + (kc - 2304));
                else if (r < 3072) { if (kc < 2304)  src = Wih0 + (size_t)r * 2304 + kc; }
                else               { if (kc >= 2304) src = Whh0 + (size_t)(r - 1024) * 1024 + (kc - 2304); }
                bf16x8 o;
                if (src) { const float4* s4 = (const float4*)src; o = pack8(s4[0], s4[1]); }
                else     { for (int k = 0; k < 8; ++k) o[k] = 0; }
                *(bf16x8*)(B0 + (size_t)r * 3328 + kc) = o;
            } else {                                    // B1 (4096 x 2048)
                int j2 = j - 1703936;
                int r = j2 >> 8;
                int kc = (j2 & 255) * 8;
                const float* src = nullptr;
                if (r < 2048)      src = (kc < 1024) ? (Wih1 + (size_t)r * 1024 + kc)
                                                     : (Whh1 + (size_t)r * 1024 + (kc - 1024));
                else if (r < 3072) { if (kc < 1024)  src = Wih1 + (size_t)r * 1024 + kc; }
                else               { if (kc >= 1024) src = Whh1 + (size_t)(r - 1024) * 1024 + (kc - 1024); }
                bf16x8 o;
                if (src) { const float4* s4 = (const float4*)src; o = pack8(s4[0], s4[1]); }
                else     { for (int k = 0; k < 8; ++k) o[k] = 0; }
                *(bf16x8*)(B1 + (size_t)r * 2048 + kc) = o;
            }
        }
    }
}

// ---------------- fused softmax + context + emb gather (fp8 es, exact decode) ----------------
__global__ __launch_bounds__(256) void k_softctx(
        const unsigned char* __restrict__ es8, const float* __restrict__ e_part,
        const float* __restrict__ emb, const int* __restrict__ x,
        float* __restrict__ attn_out, unsigned short* __restrict__ A0) {
    int n = blockIdx.x, t = threadIdx.x;
    __shared__ float as_[64];
    __shared__ float ev[64];
    {
        int s = t >> 2;
        const float* p = e_part + ((size_t)(s * 256 + n)) * 16 + (t & 3) * 4;
        float v = p[0] + p[1] + p[2] + p[3];
        v += __shfl_xor(v, 1); v += __shfl_xor(v, 2);
        if ((t & 3) == 0) ev[s] = v;
        __syncthreads();
        if (t < 64) {
            float e = ev[t];
            float mx = e;
            #pragma unroll
            for (int o = 1; o < 64; o <<= 1) mx = fmaxf(mx, __shfl_xor(mx, o));
            float ee = __expf(e - mx);
            float sum = ee;
            #pragma unroll
            for (int o = 1; o < 64; o <<= 1) sum += __shfl_xor(sum, o);
            float a = ee / sum;
            as_[t] = a;
            attn_out[t * 256 + n] = a;
        }
        __syncthreads();
    }
    float acc[8];
    #pragma unroll
    for (int k = 0; k < 8; ++k) acc[k] = 0.f;
    const unsigned char* base = es8 + (size_t)n * 2048 + t * 8;
    for (int s = 0; s < 64; ++s) {
        unsigned long long v = *(const unsigned long long*)(base + (size_t)s * 524288);
        float a = as_[s];
        #pragma unroll
        for (int k = 0; k < 8; ++k)
            acc[k] += a * e4m3f((unsigned char)(v >> (8 * k)));
    }
    bf16x8 o;
    #pragma unroll
    for (int k = 0; k < 8; ++k) o[k] = (short)f2bf(acc[k]);
    *(bf16x8*)(A0 + (size_t)n * 3328 + t * 8) = o;
    if (t < 32) {
        const float4* e4 = (const float4*)(emb + (size_t)x[n] * 256 + t * 8);
        *(bf16x8*)(A0 + (size_t)n * 3328 + 2048 + t * 8) = pack8(e4[0], e4[1]);
    }
}

// GRU gate math; sums 4 split-K partials of g: [Z][256][4096] = [r | z | i_n | h_n]
__global__ void k_gru(const float* __restrict__ g, const float* __restrict__ b_ih,
                      const float* __restrict__ b_hh, const float* __restrict__ h_in,
                      float* __restrict__ h_out, unsigned short* __restrict__ a_dst,
                      int dst_pitch) {
    int i = blockIdx.x * blockDim.x + threadIdx.x;   // 262144
    int n = i >> 10, e = i & 1023;
    const float* gn = g + (size_t)n * 4096;
    float rr = 0.f, zz = 0.f, in_ = 0.f, hn_ = 0.f;
    #pragma unroll
    for (int z = 0; z < 4; ++z) {
        const float* gz = gn + (size_t)z * 1048576;
        rr  += gz[e];
        zz  += gz[1024 + e];
        in_ += gz[2048 + e];
        hn_ += gz[3072 + e];
    }
    rr  += b_ih[e]        + b_hh[e];
    zz  += b_ih[1024 + e] + b_hh[1024 + e];
    in_ += b_ih[2048 + e];
    hn_ += b_hh[2048 + e];
    float r = 1.f / (1.f + __expf(-rr));
    float z = 1.f / (1.f + __expf(-zz));
    float ex = __expf(2.f * (in_ + r * hn_));
    float nn = 1.f - 2.f / (ex + 1.f);
    float h = h_in[i];
    float ho = (1.f - z) * nn + z * h;
    h_out[i] = ho;
    a_dst[(size_t)n * dst_pitch + e] = f2bf(ho);
}

// sum 4 split-K partials + bias (predictions: 256x128)
__global__ void k_fcsum(const float* __restrict__ Fp, const float* __restrict__ fc_b,
                        float* __restrict__ outp) {
    int i = blockIdx.x * blockDim.x + threadIdx.x;   // 32768
    outp[i] = Fp[i] + Fp[32768 + i] + Fp[65536 + i] + Fp[98304 + i] + fc_b[i & 127];
}

// ---------------- launch ----------------

extern "C" void kernel_launch(void* const* d_in, const int* in_sizes, int n_in,
                              void* d_out, int out_size, void* d_ws, size_t ws_size,
                              hipStream_t stream) {
    const int*   x      = (const int*)  d_in[0];
    const float* es     = (const float*)d_in[1];
    const float* hidden = (const float*)d_in[2];
    const float* emb    = (const float*)d_in[4];
    const float* U_w    = (const float*)d_in[5];
    const float* U_b    = (const float*)d_in[6];
    const float* W_w    = (const float*)d_in[7];
    const float* W_b    = (const float*)d_in[8];
    const float* attn_w = (const float*)d_in[9];
    const float* W_ih0  = (const float*)d_in[11];
    const float* W_hh0  = (const float*)d_in[12];
    const float* b_ih0  = (const float*)d_in[13];
    const float* b_hh0  = (const float*)d_in[14];
    const float* W_ih1  = (const float*)d_in[15];
    const float* W_hh1  = (const float*)d_in[16];
    const float* b_ih1  = (const float*)d_in[17];
    const float* b_hh1  = (const float*)d_in[18];
    const float* fc_w   = (const float*)d_in[19];
    const float* fc_b   = (const float*)d_in[20];

    float* out        = (float*)d_out;
    float* out_pred   = out;
    float* out_hidden = out + 32768;
    float* out_attn   = out + 32768 + 524288;

    char* ws = (char*)d_ws;
    size_t off = 0;
    auto alloc = [&](size_t bytes) { char* p = ws + off; off += (bytes + 255) & ~(size_t)255; return p; };
    unsigned char*  ES_F8  = (unsigned char*) alloc((size_t)16384 * 2048);
    unsigned char*  UW_F8  = (unsigned char*) alloc((size_t)1024 * 2048);
    unsigned short* WW_BF  = (unsigned short*)alloc((size_t)1024 * 1024 * 2);
    unsigned short* FCW_BF = (unsigned short*)alloc((size_t)128 * 1024 * 2);
    unsigned short* H1_BF  = (unsigned short*)alloc((size_t)256 * 1024 * 2);
    unsigned short* B0     = (unsigned short*)alloc((size_t)4096 * 3328 * 2);
    unsigned short* B1     = (unsigned short*)alloc((size_t)4096 * 2048 * 2);
    unsigned short* A0     = (unsigned short*)alloc((size_t)256 * 3328 * 2);
    unsigned short* A1     = (unsigned short*)alloc((size_t)256 * 2048 * 2);
    unsigned short* FCA    = (unsigned short*)alloc((size_t)256 * 1024 * 2);
    float* EPART = (float*)alloc((size_t)16384 * 16 * 4);
    float* WP    = (float*)alloc((size_t)4 * 256 * 1024 * 4);   // w partials; reused for fc partials
    float* G0P   = (float*)alloc((size_t)4 * 256 * 4096 * 4);   // GRU0 partials; reused for GRU1
    float* FCP   = WP;
    float* G1P   = G0P;

    // prep: conversions only (4,636,672 chunks = 18112 blocks)
    k_prep<<<18112, 256, 0, stream>>>(es, U_w, W_w, fc_w, hidden,
                                      ES_F8, UW_F8, WW_BF, FCW_BF, A0, A1, H1_BF);
    // w partials = hidden[1] @ W_w^T  (split-K 4; sum + W_b fused into u-GEMM epilogue)
    gemm_bt_sk2<<<dim3(8, 2, 4), 256, 0, stream>>>(H1_BF, WW_BF, WP, 1024, 256);
    // u-GEMM fp8 (MX K=128) + fused energy epilogue + B0/B1 ride-along tail
    gemm_energy128_f8<<<dim3(8, 128), 256, 0, stream>>>(ES_F8, UW_F8, attn_w, U_b, W_b, WP,
                                                        W_ih0, W_hh0, W_ih1, W_hh1, B0, B1, EPART);
    // softmax + context (fp8 es) + embedding -> out_attn, A0
    k_softctx<<<256, 256, 0, stream>>>(ES_F8, EPART, emb, x, out_attn, A0);
    // GRU layer 0 (split-K 4: 3328 = 4*832)
    gemm_bt_sk2<<<dim3(32, 2, 4), 256, 0, stream>>>(A0, B0, G0P, 3328, 832);
    k_gru<<<1024, 256, 0, stream>>>(G0P, b_ih0, b_hh0, hidden, out_hidden, A1, 2048);
    // GRU layer 1 (split-K 4: 2048 = 4*512)
    gemm_bt_sk2<<<dim3(32, 2, 4), 256, 0, stream>>>(A1, B1, G1P, 2048, 512);
    k_gru<<<1024, 256, 0, stream>>>(G1P, b_ih1, b_hh1, hidden + 262144, out_hidden + 262144, FCA, 1024);
    // predictions = h1 @ fc_w^T + fc_b (split-K 4: 1024 = 4*256)
    gemm_bt_sk2<<<dim3(1, 2, 4), 256, 0, stream>>>(FCA, FCW_BF, FCP, 1024, 256);
    k_fcsum<<<128, 256, 0, stream>>>(FCP, fc_b, out_pred);
}

// Round 17
// 165.716 us; speedup vs baseline: 1.0524x; 1.0524x over previous
//
#include <hip/hip_runtime.h>
#include <stdint.h>

typedef __attribute__((ext_vector_type(8))) short bf16x8;   // 8 bf16 = 4 VGPRs
typedef __attribute__((ext_vector_type(4))) float f32x4;
typedef __attribute__((ext_vector_type(8))) int i32x8;      // 32 B fp8 operand (8 VGPRs)

#define DEVI __device__ __forceinline__

DEVI unsigned short f2bf(float f) {
    union { float f; uint32_t u; } v; v.f = f;
    uint32_t r = v.u + 0x7FFFu + ((v.u >> 16) & 1u);   // RNE
    return (unsigned short)(r >> 16);
}
DEVI float bf2f(unsigned short h) {
    union { uint32_t u; float f; } v; v.u = ((uint32_t)h) << 16;
    return v.f;
}
DEVI bf16x8 pack8(float4 a, float4 b) {
    bf16x8 o;
    o[0]=(short)f2bf(a.x); o[1]=(short)f2bf(a.y); o[2]=(short)f2bf(a.z); o[3]=(short)f2bf(a.w);
    o[4]=(short)f2bf(b.x); o[5]=(short)f2bf(b.y); o[6]=(short)f2bf(b.z); o[7]=(short)f2bf(b.w);
    return o;
}

// software fp32 -> OCP e4m3fn, RNE (no API dependency)
DEVI unsigned char f2e4m3(float x) {
    union { float f; uint32_t u; } v; v.f = x;
    uint32_t sign = (v.u >> 24) & 0x80u;
    v.u &= 0x7FFFFFFFu;
    if (v.f >= 464.f) return (unsigned char)(sign | 0x7Eu);          // clamp to 448
    if (v.f < 0.0009765625f) return (unsigned char)sign;             // < 2^-10 -> 0
    uint32_t e = v.u >> 23;
    float q = __builtin_rintf(v.f * 512.f);                          // subnormal: mult of 2^-9
    uint32_t ms = (uint32_t)q;
    uint32_t subres = sign | (ms >= 8u ? 0x08u : ms);
    uint32_t r = v.u + 0x7FFFFu + ((v.u >> 20) & 1u);                // RNE to 3 mantissa bits
    uint32_t er = r >> 23;
    uint32_t normres = (er > 135u) ? (sign | 0x7Eu)
                                   : (sign | ((er - 120u) << 3) | ((r >> 20) & 7u));
    return (unsigned char)((e < 121u) ? subres : normres);
}

// exact branchless e4m3 -> fp32 (subnormals exact)
DEVI float e4m3f(unsigned char u) {
    union { uint32_t u; float f; } v;
    v.u = (((uint32_t)u & 0x80u) << 24) | (((uint32_t)u & 0x7Fu) << 20);
    return v.f * 0x1p120f;
}

#define GLOAD_LDS16(gsrc, ldst) \
    __builtin_amdgcn_global_load_lds((__attribute__((address_space(1))) void*)(gsrc), \
                                     (__attribute__((address_space(3))) void*)(ldst), 16, 0, 0)

#define BARR asm volatile("s_barrier" ::: "memory")
#define WAITV(n) asm volatile("s_waitcnt vmcnt(" #n ")" ::: "memory")

// ---------------- fused prep: conversions (fp8 + bf16 weights) + GRU weight assembly --------
__global__ void k_prep(const float* __restrict__ es, const float* __restrict__ U_w,
                       const float* __restrict__ W_w, const float* __restrict__ fc_w,
                       const float* __restrict__ hidden,
                       const float* __restrict__ Wih0, const float* __restrict__ Whh0,
                       const float* __restrict__ Wih1, const float* __restrict__ Whh1,
                       unsigned char* __restrict__ ES_F8, unsigned char* __restrict__ UW_F8,
                       unsigned short* __restrict__ WW_BF, unsigned short* __restrict__ FCW_BF,
                       unsigned short* __restrict__ A0, unsigned short* __restrict__ A1,
                       unsigned short* __restrict__ H1B,
                       unsigned short* __restrict__ B0, unsigned short* __restrict__ B1) {
    int i = blockIdx.x * blockDim.x + threadIdx.x;
    const int S0 = 4194304, S1 = S0 + 262144, S2 = S1 + 131072, S3 = S2 + 16384;
    const int S4 = S3 + 32768, S5 = S4 + 1703936, S6 = S5 + 1048576;
    if (i < S0) {
        const float4* s = (const float4*)(es + (size_t)i * 8);
        float4 a = s[0], b = s[1];
        float vv[8] = {a.x, a.y, a.z, a.w, b.x, b.y, b.z, b.w};
        unsigned long long p8 = 0;
        #pragma unroll
        for (int k = 0; k < 8; ++k) p8 |= (unsigned long long)f2e4m3(vv[k]) << (8 * k);
        *(unsigned long long*)(ES_F8 + (size_t)i * 8) = p8;
    } else if (i < S1) {
        int j = i - S0;
        const float4* s = (const float4*)(U_w + (size_t)j * 8);
        float4 a = s[0], b = s[1];
        float vv[8] = {a.x, a.y, a.z, a.w, b.x, b.y, b.z, b.w};
        unsigned long long p8 = 0;
        #pragma unroll
        for (int k = 0; k < 8; ++k) p8 |= (unsigned long long)f2e4m3(vv[k] * 16.f) << (8 * k);
        *(unsigned long long*)(UW_F8 + (size_t)j * 8) = p8;     // U_w scaled x16 (epilogue /16)
    } else if (i < S2) {
        int j = i - S1;
        const float4* s = (const float4*)(W_w + (size_t)j * 8);
        *(bf16x8*)(WW_BF + (size_t)j * 8) = pack8(s[0], s[1]);
    } else if (i < S3) {
        int j = i - S2;
        const float4* s = (const float4*)(fc_w + (size_t)j * 8);
        *(bf16x8*)(FCW_BF + (size_t)j * 8) = pack8(s[0], s[1]);
    } else if (i < S4) {
        int j = i - S3;
        int n = j >> 7, e0 = (j & 127) * 8;
        const float4* p0 = (const float4*)(hidden + (size_t)n * 1024 + e0);
        const float4* p1 = (const float4*)(hidden + 262144 + (size_t)n * 1024 + e0);
        bf16x8 o0 = pack8(p0[0], p0[1]);
        bf16x8 o1 = pack8(p1[0], p1[1]);
        *(bf16x8*)(A0 + (size_t)n * 3328 + 2304 + e0) = o0;
        *(bf16x8*)(A1 + (size_t)n * 2048 + 1024 + e0) = o1;
        *(bf16x8*)(H1B + (size_t)n * 1024 + e0) = o1;
    } else if (i < S5) {
        unsigned j = (unsigned)(i - S4);
        unsigned r = j / 416u;
        int kc = (int)(j - r * 416u) * 8;
        const float* src = nullptr;
        if (r < 2048)      src = (kc < 2304) ? (Wih0 + (size_t)r * 2304 + kc)
                                             : (Whh0 + (size_t)r * 1024 + (kc - 2304));
        else if (r < 3072) { if (kc < 2304)  src = Wih0 + (size_t)r * 2304 + kc; }
        else               { if (kc >= 2304) src = Whh0 + (size_t)(r - 1024) * 1024 + (kc - 2304); }
        bf16x8 o;
        if (src) { const float4* s4 = (const float4*)src; o = pack8(s4[0], s4[1]); }
        else     { for (int k = 0; k < 8; ++k) o[k] = 0; }
        *(bf16x8*)(B0 + (size_t)r * 3328 + kc) = o;
    } else if (i < S6) {
        int j = i - S5;
        int r = j >> 8;
        int kc = (j & 255) * 8;
        const float* src = nullptr;
        if (r < 2048)      src = (kc < 1024) ? (Wih1 + (size_t)r * 1024 + kc)
                                             : (Whh1 + (size_t)r * 1024 + (kc - 1024));
        else if (r < 3072) { if (kc < 1024)  src = Wih1 + (size_t)r * 1024 + kc; }
        else               { if (kc >= 1024) src = Whh1 + (size_t)(r - 1024) * 1024 + (kc - 1024); }
        bf16x8 o;
        if (src) { const float4* s4 = (const float4*)src; o = pack8(s4[0], s4[1]); }
        else     { for (int k = 0; k < 8; ++k) o[k] = 0; }
        *(bf16x8*)(B1 + (size_t)r * 2048 + kc) = o;
    }
}

// ---------------- split-K GEMM, R8 shell: Cpart[z] = A(MxK[slice z]) * B(NxK)^T (bf16) -------
__global__ __launch_bounds__(256) void gemm_bt_sk2(
        const unsigned short* __restrict__ A, const unsigned short* __restrict__ B,
        float* __restrict__ Cpart, int K, int ksl) {
    __shared__ __align__(16) char lds[65536];           // 2 slots x 32 KiB
    const int NTT = ksl >> 6;

    const int t = threadIdx.x;
    const int w = t >> 6, lane = t & 63;
    const int wm = w >> 1, wn = w & 1;
    const int lg = lane >> 4, r16 = lane & 15;
    const int z = blockIdx.z;
    const int nbx = gridDim.x;
    const int N = nbx * 128, M = gridDim.y * 128;

    int d = blockIdx.y * nbx + blockIdx.x;
    int f = d;
    int nwg = nbx * gridDim.y;
    if ((nwg & 7) == 0) { int cpx = nwg >> 3; f = (d & 7) * cpx + (d >> 3); }
    const int bx = f % nbx, by = f / nbx;
    const int row0 = by * 128, col0 = bx * 128;

    const unsigned short* gsrc[8];
    unsigned lodst[8];
    #pragma unroll
    for (int q = 0; q < 8; ++q) {
        int isB = q >> 2, rq = q & 3;
        int row = rq * 32 + w * 8 + (lane >> 3);
        int slot = (lane & 7) ^ (lane >> 3);
        gsrc[q] = (isB ? B + (size_t)(col0 + row) * K
                       : A + (size_t)(row0 + row) * K) + (size_t)z * ksl + slot * 8;
        lodst[q] = (unsigned)(isB * 16384 + (rq * 32 + w * 8) * 128);
    }

#define STAGE(T) do { \
    char* lp_ = lds + ((T) & 1) * 32768; \
    _Pragma("unroll") \
    for (int q_ = 0; q_ < 8; ++q_) \
        GLOAD_LDS16(gsrc[q_] + (size_t)(T) * 64, lp_ + lodst[q_]); \
} while (0)

    const unsigned swz = (unsigned)((r16 & 7) << 4);
    unsigned aoff[4], boff[4];
    #pragma unroll
    for (int m = 0; m < 4; ++m)
        aoff[m] = ((unsigned)((wm * 64 + m * 16 + r16) * 128 + lg * 16)) ^ swz;
    #pragma unroll
    for (int n = 0; n < 4; ++n)
        boff[n] = 16384u + (((unsigned)((wn * 64 + n * 16 + r16) * 128 + lg * 16)) ^ swz);

    f32x4 acc[4][4];
    #pragma unroll
    for (int m = 0; m < 4; ++m)
        #pragma unroll
        for (int n = 0; n < 4; ++n)
            #pragma unroll
            for (int q = 0; q < 4; ++q) acc[m][n][q] = 0.0f;

    STAGE(0);
    #pragma unroll 1
    for (int tt = 0; tt < NTT; ++tt) {
        if (tt + 1 < NTT) { STAGE(tt + 1); WAITV(8); }
        else              { WAITV(0); }
        BARR;
        const char* lp = lds + (tt & 1) * 32768;
        #pragma unroll
        for (int kk = 0; kk < 2; ++kk) {
            bf16x8 afr[4], bfr[4];
            #pragma unroll
            for (int n = 0; n < 4; ++n) bfr[n] = *(const bf16x8*)(lp + (boff[n] ^ (kk << 6)));
            #pragma unroll
            for (int m = 0; m < 4; ++m) afr[m] = *(const bf16x8*)(lp + (aoff[m] ^ (kk << 6)));
            #pragma unroll
            for (int m = 0; m < 4; ++m)
                #pragma unroll
                for (int n = 0; n < 4; ++n)
                    acc[m][n] = __builtin_amdgcn_mfma_f32_16x16x32_bf16(
                        afr[m], bfr[n], acc[m][n], 0, 0, 0);
        }
        BARR;
    }
#undef STAGE

    float* Cz = Cpart + (size_t)z * (size_t)M * N;
    #pragma unroll
    for (int m = 0; m < 4; ++m)
        #pragma unroll
        for (int n = 0; n < 4; ++n)
            #pragma unroll
            for (int q = 0; q < 4; ++q) {
                int row = row0 + wm * 64 + m * 16 + lg * 4 + q;
                int col = col0 + wn * 64 + n * 16 + r16;
                Cz[(size_t)row * N + col] = acc[m][n][q];
            }
}

// ---------------- u-GEMM fp8, MX-scaled K=128 MFMA (unit scales), R12 read slots ------------
// A = es_fp8 (16384 x 2048); B = U_w_fp8 x16 (1024 x 2048). grid (8, 128), 256 thr, 4 waves.
// Read slots: R12's measured-0-conflict pattern (int4 at ((sel*4+lg)^(r16&7))<<4). Operand =
// {slot lg, slot lg+4}: a (lane,byte)->k bijection applied identically to A and B, so the
// contraction is unchanged. One v_mfma_scale_f32_16x16x128_f8f6f4 per (m,n) per tile, unit
// E8M0 scales (0x7F = 2^0) -> semantically plain fp8 GEMM at 2x rate, 4x fewer MFMA issues.
__global__ __launch_bounds__(256) void gemm_energy128_f8(
        const unsigned char* __restrict__ A, const unsigned char* __restrict__ B,
        const float* __restrict__ attn_w, const float* __restrict__ U_b,
        const float* __restrict__ W_b, const float* __restrict__ WP,
        float* __restrict__ e_part) {
    const int NTT = 16;                                 // 2048 / 128, full K
    __shared__ __align__(16) char lds[65536];

    const int t = threadIdx.x;
    const int w = t >> 6, lane = t & 63;
    const int wm = w >> 1, wn = w & 1;
    const int lg = lane >> 4, r16 = lane & 15;

    int d = blockIdx.y * gridDim.x + blockIdx.x;        // 1024 blocks
    int f = (d & 7) * 128 + (d >> 3);                   // bijective XCD swizzle
    const int bx = f & 7, by = f >> 3;
    const int row0 = by * 128, col0 = bx * 128;

    const unsigned char* gsrc[8];
    unsigned lodst[8];
    #pragma unroll
    for (int q = 0; q < 8; ++q) {
        int isB = q >> 2, rq = q & 3;
        int row = rq * 32 + w * 8 + (lane >> 3);
        int slot = (lane & 7) ^ (lane >> 3);
        gsrc[q] = (isB ? B + (size_t)(col0 + row) * 2048
                       : A + (size_t)(row0 + row) * 2048) + slot * 16;
        lodst[q] = (unsigned)(isB * 16384 + (rq * 32 + w * 8) * 128);
    }

#define STAGE(T) do { \
    char* lp_ = lds + ((T) & 1) * 32768; \
    _Pragma("unroll") \
    for (int q_ = 0; q_ < 8; ++q_) \
        GLOAD_LDS16(gsrc[q_] + (size_t)(T) * 128, lp_ + lodst[q_]); \
} while (0)

    // R12-proven 0-conflict read slots: sel in {0,1} -> logical slot sel*4+lg, swz ^ (r16&7)
    unsigned s16[2];
    #pragma unroll
    for (int sel = 0; sel < 2; ++sel)
        s16[sel] = (unsigned)(((sel * 4 + lg) ^ (r16 & 7)) << 4);
    unsigned arow[4], brow[4];
    #pragma unroll
    for (int m = 0; m < 4; ++m) arow[m] = (unsigned)((wm * 64 + m * 16 + r16) * 128);
    #pragma unroll
    for (int n = 0; n < 4; ++n) brow[n] = 16384u + (unsigned)((wn * 64 + n * 16 + r16) * 128);

    f32x4 acc[4][4];
    #pragma unroll
    for (int m = 0; m < 4; ++m)
        #pragma unroll
        for (int n = 0; n < 4; ++n)
            #pragma unroll
            for (int q = 0; q < 4; ++q) acc[m][n][q] = 0.0f;

    STAGE(0);
    #pragma unroll 1
    for (int tt = 0; tt < NTT; ++tt) {
        if (tt + 1 < NTT) { STAGE(tt + 1); WAITV(8); }
        else              { WAITV(0); }
        BARR;
        const char* lp = lds + (tt & 1) * 32768;
        i32x8 a8[4], b8[4];
        #pragma unroll
        for (int n = 0; n < 4; ++n) {
            int4 lo = *(const int4*)(lp + brow[n] + s16[0]);
            int4 hi = *(const int4*)(lp + brow[n] + s16[1]);
            b8[n] = (i32x8){lo.x, lo.y, lo.z, lo.w, hi.x, hi.y, hi.z, hi.w};
        }
        #pragma unroll
        for (int m = 0; m < 4; ++m) {
            int4 lo = *(const int4*)(lp + arow[m] + s16[0]);
            int4 hi = *(const int4*)(lp + arow[m] + s16[1]);
            a8[m] = (i32x8){lo.x, lo.y, lo.z, lo.w, hi.x, hi.y, hi.z, hi.w};
        }
        #pragma unroll
        for (int m = 0; m < 4; ++m)
            #pragma unroll
            for (int n = 0; n < 4; ++n)
                acc[m][n] = __builtin_amdgcn_mfma_scale_f32_16x16x128_f8f6f4(
                    a8[m], b8[n], acc[m][n], 0, 0,
                    0, 0x7F7F7F7F, 0, 0x7F7F7F7F);     // unit E8M0 scales -> plain fp8
        BARR;
    }
#undef STAGE

    // fused energy epilogue; u = acc/16; w = 4 split-K partials + W_b inline (WP L2-resident)
    float aw[4], ub[4];
    #pragma unroll
    for (int n = 0; n < 4; ++n) {
        int col = col0 + wn * 64 + n * 16 + r16;
        aw[n] = attn_w[col];
        ub[n] = U_b[col] + W_b[col];
    }
    #pragma unroll
    for (int m = 0; m < 4; ++m)
        #pragma unroll
        for (int q = 0; q < 4; ++q) {
            int row = row0 + wm * 64 + m * 16 + lg * 4 + q;
            const float* wrow = WP + (size_t)(row & 255) * 1024;
            float e = 0.f;
            #pragma unroll
            for (int n = 0; n < 4; ++n) {
                int col = col0 + wn * 64 + n * 16 + r16;
                float wv = wrow[col] + wrow[262144 + col] + wrow[524288 + col] + wrow[786432 + col];
                float cc = acc[m][n][q] * 0.0625f + ub[n] + wv;
                float ex = __expf(2.f * cc);               // tanh via exp
                e += aw[n] * (1.f - 2.f / (ex + 1.f));
            }
            e += __shfl_xor(e, 1); e += __shfl_xor(e, 2);
            e += __shfl_xor(e, 4); e += __shfl_xor(e, 8);
            if (r16 == 0) e_part[(size_t)row * 16 + bx * 2 + wn] = e;
        }
}

// ---------------- fused softmax + context + emb gather (fp8 es, exact decode) ----------------
__global__ __launch_bounds__(256) void k_softctx(
        const unsigned char* __restrict__ es8, const float* __restrict__ e_part,
        const float* __restrict__ emb, const int* __restrict__ x,
        float* __restrict__ attn_out, unsigned short* __restrict__ A0) {
    int n = blockIdx.x, t = threadIdx.x;
    __shared__ float as_[64];
    __shared__ float ev[64];
    {
        int s = t >> 2;
        const float* p = e_part + ((size_t)(s * 256 + n)) * 16 + (t & 3) * 4;
        float v = p[0] + p[1] + p[2] + p[3];
        v += __shfl_xor(v, 1); v += __shfl_xor(v, 2);
        if ((t & 3) == 0) ev[s] = v;
        __syncthreads();
        if (t < 64) {
            float e = ev[t];
            float mx = e;
            #pragma unroll
            for (int o = 1; o < 64; o <<= 1) mx = fmaxf(mx, __shfl_xor(mx, o));
            float ee = __expf(e - mx);
            float sum = ee;
            #pragma unroll
            for (int o = 1; o < 64; o <<= 1) sum += __shfl_xor(sum, o);
            float a = ee / sum;
            as_[t] = a;
            attn_out[t * 256 + n] = a;
        }
        __syncthreads();
    }
    float acc[8];
    #pragma unroll
    for (int k = 0; k < 8; ++k) acc[k] = 0.f;
    const unsigned char* base = es8 + (size_t)n * 2048 + t * 8;
    for (int s = 0; s < 64; ++s) {
        unsigned long long v = *(const unsigned long long*)(base + (size_t)s * 524288);
        float a = as_[s];
        #pragma unroll
        for (int k = 0; k < 8; ++k)
            acc[k] += a * e4m3f((unsigned char)(v >> (8 * k)));
    }
    bf16x8 o;
    #pragma unroll
    for (int k = 0; k < 8; ++k) o[k] = (short)f2bf(acc[k]);
    *(bf16x8*)(A0 + (size_t)n * 3328 + t * 8) = o;
    if (t < 32) {
        const float4* e4 = (const float4*)(emb + (size_t)x[n] * 256 + t * 8);
        *(bf16x8*)(A0 + (size_t)n * 3328 + 2048 + t * 8) = pack8(e4[0], e4[1]);
    }
}

// GRU gate math; sums 4 split-K partials of g: [Z][256][4096] = [r | z | i_n | h_n]
__global__ void k_gru(const float* __restrict__ g, const float* __restrict__ b_ih,
                      const float* __restrict__ b_hh, const float* __restrict__ h_in,
                      float* __restrict__ h_out, unsigned short* __restrict__ a_dst,
                      int dst_pitch) {
    int i = blockIdx.x * blockDim.x + threadIdx.x;   // 262144
    int n = i >> 10, e = i & 1023;
    const float* gn = g + (size_t)n * 4096;
    float rr = 0.f, zz = 0.f, in_ = 0.f, hn_ = 0.f;
    #pragma unroll
    for (int z = 0; z < 4; ++z) {
        const float* gz = gn + (size_t)z * 1048576;
        rr  += gz[e];
        zz  += gz[1024 + e];
        in_ += gz[2048 + e];
        hn_ += gz[3072 + e];
    }
    rr  += b_ih[e]        + b_hh[e];
    zz  += b_ih[1024 + e] + b_hh[1024 + e];
    in_ += b_ih[2048 + e];
    hn_ += b_hh[2048 + e];
    float r = 1.f / (1.f + __expf(-rr));
    float z = 1.f / (1.f + __expf(-zz));
    float ex = __expf(2.f * (in_ + r * hn_));
    float nn = 1.f - 2.f / (ex + 1.f);
    float h = h_in[i];
    float ho = (1.f - z) * nn + z * h;
    h_out[i] = ho;
    a_dst[(size_t)n * dst_pitch + e] = f2bf(ho);
}

// sum 4 split-K partials + bias (predictions: 256x128)
__global__ void k_fcsum(const float* __restrict__ Fp, const float* __restrict__ fc_b,
                        float* __restrict__ outp) {
    int i = blockIdx.x * blockDim.x + threadIdx.x;   // 32768
    outp[i] = Fp[i] + Fp[32768 + i] + Fp[65536 + i] + Fp[98304 + i] + fc_b[i & 127];
}

// ---------------- launch ----------------

extern "C" void kernel_launch(void* const* d_in, const int* in_sizes, int n_in,
                              void* d_out, int out_size, void* d_ws, size_t ws_size,
                              hipStream_t stream) {
    const int*   x      = (const int*)  d_in[0];
    const float* es     = (const float*)d_in[1];
    const float* hidden = (const float*)d_in[2];
    const float* emb    = (const float*)d_in[4];
    const float* U_w    = (const float*)d_in[5];
    const float* U_b    = (const float*)d_in[6];
    const float* W_w    = (const float*)d_in[7];
    const float* W_b    = (const float*)d_in[8];
    const float* attn_w = (const float*)d_in[9];
    const float* W_ih0  = (const float*)d_in[11];
    const float* W_hh0  = (const float*)d_in[12];
    const float* b_ih0  = (const float*)d_in[13];
    const float* b_hh0  = (const float*)d_in[14];
    const float* W_ih1  = (const float*)d_in[15];
    const float* W_hh1  = (const float*)d_in[16];
    const float* b_ih1  = (const float*)d_in[17];
    const float* b_hh1  = (const float*)d_in[18];
    const float* fc_w   = (const float*)d_in[19];
    const float* fc_b   = (const float*)d_in[20];

    float* out        = (float*)d_out;
    float* out_pred   = out;
    float* out_hidden = out + 32768;
    float* out_attn   = out + 32768 + 524288;

    char* ws = (char*)d_ws;
    size_t off = 0;
    auto alloc = [&](size_t bytes) { char* p = ws + off; off += (bytes + 255) & ~(size_t)255; return p; };
    unsigned char*  ES_F8  = (unsigned char*) alloc((size_t)16384 * 2048);
    unsigned char*  UW_F8  = (unsigned char*) alloc((size_t)1024 * 2048);
    unsigned short* WW_BF  = (unsigned short*)alloc((size_t)1024 * 1024 * 2);
    unsigned short* FCW_BF = (unsigned short*)alloc((size_t)128 * 1024 * 2);
    unsigned short* H1_BF  = (unsigned short*)alloc((size_t)256 * 1024 * 2);
    unsigned short* B0     = (unsigned short*)alloc((size_t)4096 * 3328 * 2);
    unsigned short* B1     = (unsigned short*)alloc((size_t)4096 * 2048 * 2);
    unsigned short* A0     = (unsigned short*)alloc((size_t)256 * 3328 * 2);
    unsigned short* A1     = (unsigned short*)alloc((size_t)256 * 2048 * 2);
    unsigned short* FCA    = (unsigned short*)alloc((size_t)256 * 1024 * 2);
    float* EPART = (float*)alloc((size_t)16384 * 16 * 4);
    float* WP    = (float*)alloc((size_t)4 * 256 * 1024 * 4);   // w partials; reused for fc partials
    float* G0P   = (float*)alloc((size_t)4 * 256 * 4096 * 4);   // GRU0 partials; reused for GRU1
    float* FCP   = WP;
    float* G1P   = G0P;

    // fused prep (7,389,184 chunks = 28864 blocks)
    k_prep<<<28864, 256, 0, stream>>>(es, U_w, W_w, fc_w, hidden, W_ih0, W_hh0, W_ih1, W_hh1,
                                      ES_F8, UW_F8, WW_BF, FCW_BF, A0, A1, H1_BF, B0, B1);
    // w partials = hidden[1] @ W_w^T  (split-K 4; sum + W_b fused into u-GEMM epilogue)
    gemm_bt_sk2<<<dim3(8, 2, 4), 256, 0, stream>>>(H1_BF, WW_BF, WP, 1024, 256);
    // u-GEMM fp8 (MX K=128, unit scales, R12 read slots) + fused energy epilogue
    gemm_energy128_f8<<<dim3(8, 128), 256, 0, stream>>>(ES_F8, UW_F8, attn_w, U_b, W_b, WP, EPART);
    // softmax + context (fp8 es) + embedding -> out_attn, A0
    k_softctx<<<256, 256, 0, stream>>>(ES_F8, EPART, emb, x, out_attn, A0);
    // GRU layer 0 (split-K 4: 3328 = 4*832)
    gemm_bt_sk2<<<dim3(32, 2, 4), 256, 0, stream>>>(A0, B0, G0P, 3328, 832);
    k_gru<<<1024, 256, 0, stream>>>(G0P, b_ih0, b_hh0, hidden, out_hidden, A1, 2048);
    // GRU layer 1 (split-K 4: 2048 = 4*512)
    gemm_bt_sk2<<<dim3(32, 2, 4), 256, 0, stream>>>(A1, B1, G1P, 2048, 512);
    k_gru<<<1024, 256, 0, stream>>>(G1P, b_ih1, b_hh1, hidden + 262144, out_hidden + 262144, FCA, 1024);
    // predictions = h1 @ fc_w^T + fc_b (split-K 4: 1024 = 4*256)
    gemm_bt_sk2<<<dim3(1, 2, 4), 256, 0, stream>>>(FCA, FCW_BF, FCP, 1024, 256);
    k_fcsum<<<128, 256, 0, stream>>>(FCP, fc_b, out_pred);
}